// Round 15
// baseline (82.720 us; speedup 1.0000x reference)
//
#include <hip/hip_runtime.h>
#include <hip/hip_bf16.h>

// GATConv on MI355X.
// Pipeline (2 kernels):
//   kA: blocks [0,4096): pack adj (64MB int32) -> 2MB bitmask, tile-transposed
//       [i>>5][jw][i&31]; 8 rows/wave-iter for MLP. PACK BLOCKS DISPATCH FIRST
//       (they are the HBM-bound long pole; starting the 64MB stream immediately
//       overlaps it with the GEMM compute that fills in behind).
//       blocks [4096,4608): x_l 64-row x 1-head tile GEMM (bf16 MFMA). Epilogue
//       writes x_l in MFMA B-fragment order xlS[h][jw][s][n][lane][8] + per-head
//       alpha_l/r (alpha_l pre-scaled log2e).
//   k3: R14 verbatim (proven plateau: 45.2us; TLP x2 null, ILP pipeline defeated
//       by regalloc, line-halving negative, setprio ~ +1%).
//       block = (head, i-tile 32), 8 waves = 8 j-eighths.
//       Mask via sbfe on complemented word -> bias 0/-1000 (2 VALU/elem).
//       P = exp2(fma(al2, ar, bias)) in MFMA A-frag layout; acc += P @ x_l;
//       Z via MFMA ones-B. 2-phase x 3-round LDS tree reduce,
//       out = relu(acc*rcp(Z)).
//   grid.x = 8 heads = 8 XCDs -> per-head xlS L2 locality.

#define NN    4096
#define NF    512
#define NH    8
#define CC    64
#define HC    512   // NH*CC
#define GEMM_BLOCKS 512
#define PACK_BLOCKS 4096

typedef __bf16 bf16x8 __attribute__((ext_vector_type(8)));
typedef __bf16 bf16x4 __attribute__((ext_vector_type(4)));
typedef float  f32x4  __attribute__((ext_vector_type(4)));
typedef unsigned int u32;
typedef unsigned long long u64;

__device__ __forceinline__ float exp2_raw(float x) {
    float r;
    asm("v_exp_f32 %0, %1" : "=v"(r) : "v"(x));
    return r;
}

#if __has_builtin(__builtin_amdgcn_sbfe)
#define SBFE1(x, off) __builtin_amdgcn_sbfe((int)(x), (off), 1)
#else
#define SBFE1(x, off) (((int)((u32)(x) << (31 - (off)))) >> 31)
#endif

// bias from COMPLEMENTED word: bit e of wnot set (edge absent) -> -1000.0f else 0.
__device__ __forceinline__ float mask_bias(u32 wnot, int e) {
    return __uint_as_float(((u32)SBFE1(wnot, e)) & 0xC47A0000u);
}

// ---------------- kA: fused pack + projection GEMM + frag-layout store ----------------
__global__ __launch_bounds__(256) void kA(
    const int* __restrict__ adj, u64* __restrict__ bits,
    const float* __restrict__ X, const float* __restrict__ W,
    const float* __restrict__ bias, const float* __restrict__ attl,
    const float* __restrict__ attr, __bf16* __restrict__ xlS,
    float* __restrict__ alT, float* __restrict__ arT)
{
    const int tid = threadIdx.x;

    if (blockIdx.x < PACK_BLOCKS) {
        // ---- pack path (dispatched FIRST): 8 rows per wave-iter, bitmask out ----
        const int bid  = blockIdx.x;
        const int lane = tid & 63;
        const int wid  = bid * 4 + (tid >> 6);      // 16384 waves
        for (int u = wid; u < 32768; u += 16384) {  // (4096/8 rowgroups) * 64 jw
            const int i0 = (u >> 6) * 8;
            const int jw = u & 63;
            const int ja = jw * 64 + lane;
            const u64 b0 = __ballot(adj[(i0 + 0) * NN + ja] != 0);
            const u64 b1 = __ballot(adj[(i0 + 1) * NN + ja] != 0);
            const u64 b2 = __ballot(adj[(i0 + 2) * NN + ja] != 0);
            const u64 b3 = __ballot(adj[(i0 + 3) * NN + ja] != 0);
            const u64 b4 = __ballot(adj[(i0 + 4) * NN + ja] != 0);
            const u64 b5 = __ballot(adj[(i0 + 5) * NN + ja] != 0);
            const u64 b6 = __ballot(adj[(i0 + 6) * NN + ja] != 0);
            const u64 b7 = __ballot(adj[(i0 + 7) * NN + ja] != 0);
            if (lane < 8) {
                const int r = lane;
                const u64 wr = (r < 4) ? ((r < 2) ? (r < 1 ? b0 : b1) : (r < 3 ? b2 : b3))
                                       : ((r < 6) ? (r < 5 ? b4 : b5) : (r < 7 ? b6 : b7));
                const int i = i0 + r;
                bits[((i >> 5) * 64 + jw) * 32 + (i & 31)] = wr;
            }
        }
        return;
    }

    // ---- GEMM path: one (64-node, 1-head) tile ----
    __shared__ __bf16 As[64][40];
    __shared__ __bf16 BsT[64][40];
    __shared__ __bf16 T[64][72];

    const int gb = blockIdx.x - PACK_BLOCKS;   // 0..511
    const int w  = tid >> 6;
    const int l  = tid & 63;
    const int lo = l & 15;
    const int hi = l >> 4;
    const int r0 = (gb & 63) * 64;   // node base == jw*64
    const int h  = gb >> 6;
    const int c0 = h * CC;
    const int wm = (w >> 1) * 32;
    const int wn = (w & 1) * 32;

    f32x4 acc[2][2];
#pragma unroll
    for (int m = 0; m < 2; ++m)
#pragma unroll
        for (int n = 0; n < 2; ++n) acc[m][n] = (f32x4){0.f, 0.f, 0.f, 0.f};

    const int arow = tid >> 3;
    const int acol = (tid & 7) * 4;
    const int brow = tid >> 4;
    const int bcol = (tid & 15) * 4;

    for (int k0 = 0; k0 < NF; k0 += 32) {
        __syncthreads();
#pragma unroll
        for (int p = 0; p < 2; ++p) {
            int r = arow + p * 32;
            float4 v = *reinterpret_cast<const float4*>(&X[(r0 + r) * NF + k0 + acol]);
            bf16x4 av;
            av[0] = (__bf16)v.x; av[1] = (__bf16)v.y; av[2] = (__bf16)v.z; av[3] = (__bf16)v.w;
            *reinterpret_cast<bf16x4*>(&As[r][acol]) = av;
        }
#pragma unroll
        for (int p = 0; p < 2; ++p) {
            int kk = brow + p * 16;
            float4 v = *reinterpret_cast<const float4*>(&W[(k0 + kk) * HC + c0 + bcol]);
            BsT[bcol + 0][kk] = (__bf16)v.x;
            BsT[bcol + 1][kk] = (__bf16)v.y;
            BsT[bcol + 2][kk] = (__bf16)v.z;
            BsT[bcol + 3][kk] = (__bf16)v.w;
        }
        __syncthreads();

        bf16x8 a[2], b[2];
#pragma unroll
        for (int m = 0; m < 2; ++m)
            a[m] = *reinterpret_cast<const bf16x8*>(&As[wm + m * 16 + lo][hi * 8]);
#pragma unroll
        for (int n = 0; n < 2; ++n)
            b[n] = *reinterpret_cast<const bf16x8*>(&BsT[wn + n * 16 + lo][hi * 8]);
#pragma unroll
        for (int m = 0; m < 2; ++m)
#pragma unroll
            for (int n = 0; n < 2; ++n)
                acc[m][n] = __builtin_amdgcn_mfma_f32_16x16x32_bf16(a[m], b[n], acc[m][n], 0, 0, 0);
    }

    // epilogue: bias + bf16 round into LDS tile T[node-in-tile][channel]
    __syncthreads();
#pragma unroll
    for (int n = 0; n < 2; ++n) {
        const float bv = bias[c0 + wn + n * 16 + lo];
#pragma unroll
        for (int m = 0; m < 2; ++m)
#pragma unroll
            for (int r = 0; r < 4; ++r)
                T[wm + m * 16 + hi * 4 + r][wn + n * 16 + lo] = (__bf16)(acc[m][n][r] + bv);
    }
    __syncthreads();

    // store in k3's B-fragment order: xlS[((h*64+jw)*2+s)*4+n][lane][8]
    {
        const int jw = gb & 63;
#pragma unroll
        for (int p = 0; p < 2; ++p) {
            const int z   = tid + p * 256;
            const int s   = z >> 8;
            const int n   = (z >> 6) & 3;
            const int ln  = z & 63;
            const int hi2 = ln >> 4;
            const int lo2 = ln & 15;
            bf16x8 g;
#pragma unroll
            for (int e = 0; e < 8; ++e)
                g[e] = T[s * 32 + hi2 * 8 + e][n * 16 + lo2];
            *reinterpret_cast<bf16x8*>(
                &xlS[(size_t)((((h * 64 + jw) * 2 + s) * 4 + n) * 64 + ln) * 8]) = g;
        }
    }
    // alpha_l (scaled by log2e) / alpha_r for these 64 nodes
    {
        const int row = tid >> 2;
        const int q   = tid & 3;
        float pl = 0.f, pr = 0.f;
#pragma unroll
        for (int c = 0; c < 16; ++c) {
            const int cc = q * 16 + c;
            const float f = (float)T[row][cc];
            pl += f * attl[c0 + cc];
            pr += f * attr[c0 + cc];
        }
        pl += __shfl_xor(pl, 1); pl += __shfl_xor(pl, 2);
        pr += __shfl_xor(pr, 1); pr += __shfl_xor(pr, 2);
        if (q == 0) {
            alT[h * NN + r0 + row] = pl * 1.4426950408889634f;
            arT[h * NN + r0 + row] = pr;
        }
    }
}

// ---------------- k3: fused mask+exp+aggregate+Z+normalize+ReLU ----------------
__global__ __launch_bounds__(512) void k3_attn(
    const u64* __restrict__ bits, const __bf16* __restrict__ xlS,
    const float* __restrict__ alT, const float* __restrict__ arT,
    float* __restrict__ out)
{
    __shared__ float rb[4][64][21];   // [slot][lane][payload+pad] = 21.5 KB

    const int tid = threadIdx.x;
    const int wv  = tid >> 6;        // 8 waves : j-eighths
    const int l   = tid & 63;
    const int lo  = l & 15;
    const int hi  = l >> 4;
    const int h   = blockIdx.x;      // head (== XCD via round-robin dispatch)
    const int i0  = blockIdx.y * 32;
    const int off = hi * 8;          // bit offset within 32-bit mask word

    const float al20 = alT[h * NN + i0 + lo];
    const float al21 = alT[h * NN + i0 + 16 + lo];

    f32x4 acc[2][4];
    f32x4 accz[2];
#pragma unroll
    for (int m = 0; m < 2; ++m) {
        accz[m] = (f32x4){0.f, 0.f, 0.f, 0.f};
#pragma unroll
        for (int n = 0; n < 4; ++n) acc[m][n] = (f32x4){0.f, 0.f, 0.f, 0.f};
    }
    bf16x8 ones;
#pragma unroll
    for (int j = 0; j < 8; ++j) ones[j] = (__bf16)1.0f;

    const float* arp = &arT[h * NN];
    const __bf16* xs = xlS + (size_t)h * (64 * 4096);
    const u64* bT = bits + (size_t)blockIdx.y * 64 * 32;
    const int w0 = wv * 8;

#pragma unroll
    for (int it = 0; it < 8; ++it) {
        const int jw = w0 + it;
        const u64 ab0 = bT[jw * 32 + lo];
        const u64 ab1 = bT[jw * 32 + 16 + lo];
#pragma unroll
        for (int s = 0; s < 2; ++s) {
            const int jj = jw * 64 + s * 32 + hi * 8;
            const f32x4 rv0 = *reinterpret_cast<const f32x4*>(arp + jj);
            const f32x4 rv1 = *reinterpret_cast<const f32x4*>(arp + jj + 4);
            bf16x8 bX[4];
#pragma unroll
            for (int n = 0; n < 4; ++n)
                bX[n] = *reinterpret_cast<const bf16x8*>(
                    &xs[(jw * 2 + s) * 2048 + n * 512 + l * 8]);
            // boost this wave while it's in the exp+MFMA cluster (waves here are
            // barrier-free -> role diversity across the CU; T5 regime)
            __builtin_amdgcn_s_setprio(1);
#pragma unroll
            for (int m = 0; m < 2; ++m) {
                // 32-bit mask word for this (m, s); shift then COMPLEMENT so
                // sbfe(wnot, e) = 0 when the edge exists (bias 0), -1 when absent.
                const u32 word = (u32)((m ? ab1 : ab0) >> (s * 32));
                const u32 wnot = ~(word >> off);
                const float alm = m ? al21 : al20;
                const float p0 = exp2_raw(__builtin_fmaf(alm, rv0[0], mask_bias(wnot, 0)));
                const float p1 = exp2_raw(__builtin_fmaf(alm, rv0[1], mask_bias(wnot, 1)));
                const float p2 = exp2_raw(__builtin_fmaf(alm, rv0[2], mask_bias(wnot, 2)));
                const float p3 = exp2_raw(__builtin_fmaf(alm, rv0[3], mask_bias(wnot, 3)));
                const float p4 = exp2_raw(__builtin_fmaf(alm, rv1[0], mask_bias(wnot, 4)));
                const float p5 = exp2_raw(__builtin_fmaf(alm, rv1[1], mask_bias(wnot, 5)));
                const float p6 = exp2_raw(__builtin_fmaf(alm, rv1[2], mask_bias(wnot, 6)));
                const float p7 = exp2_raw(__builtin_fmaf(alm, rv1[3], mask_bias(wnot, 7)));
                bf16x8 aP;
                aP[0] = (__bf16)p0; aP[1] = (__bf16)p1; aP[2] = (__bf16)p2; aP[3] = (__bf16)p3;
                aP[4] = (__bf16)p4; aP[5] = (__bf16)p5; aP[6] = (__bf16)p6; aP[7] = (__bf16)p7;
                accz[m] = __builtin_amdgcn_mfma_f32_16x16x32_bf16(aP, ones, accz[m], 0, 0, 0);
#pragma unroll
                for (int n = 0; n < 4; ++n)
                    acc[m][n] = __builtin_amdgcn_mfma_f32_16x16x32_bf16(aP, bX[n], acc[m][n], 0, 0, 0);
            }
            __builtin_amdgcn_s_setprio(0);
        }
    }

    // ---- 2-phase x 3-round LDS tree reduce across 8 waves ----
#pragma unroll
    for (int m = 0; m < 2; ++m) {
        if (wv >= 4) {
#pragma unroll
            for (int n = 0; n < 4; ++n)
#pragma unroll
                for (int r = 0; r < 4; ++r)
                    rb[wv - 4][l][n * 4 + r] = acc[m][n][r];
#pragma unroll
            for (int r = 0; r < 4; ++r)
                rb[wv - 4][l][16 + r] = accz[m][r];
        }
        __syncthreads();
        if (wv < 4) {
#pragma unroll
            for (int n = 0; n < 4; ++n)
#pragma unroll
                for (int r = 0; r < 4; ++r)
                    acc[m][n][r] += rb[wv][l][n * 4 + r];
#pragma unroll
            for (int r = 0; r < 4; ++r)
                accz[m][r] += rb[wv][l][16 + r];
        }
        __syncthreads();
        if (wv >= 2 && wv < 4) {
#pragma unroll
            for (int n = 0; n < 4; ++n)
#pragma unroll
                for (int r = 0; r < 4; ++r)
                    rb[wv - 2][l][n * 4 + r] = acc[m][n][r];
#pragma unroll
            for (int r = 0; r < 4; ++r)
                rb[wv - 2][l][16 + r] = accz[m][r];
        }
        __syncthreads();
        if (wv < 2) {
#pragma unroll
            for (int n = 0; n < 4; ++n)
#pragma unroll
                for (int r = 0; r < 4; ++r)
                    acc[m][n][r] += rb[wv][l][n * 4 + r];
#pragma unroll
            for (int r = 0; r < 4; ++r)
                accz[m][r] += rb[wv][l][16 + r];
        }
        __syncthreads();
        if (wv == 1) {
#pragma unroll
            for (int n = 0; n < 4; ++n)
#pragma unroll
                for (int r = 0; r < 4; ++r)
                    rb[0][l][n * 4 + r] = acc[m][n][r];
#pragma unroll
            for (int r = 0; r < 4; ++r)
                rb[0][l][16 + r] = accz[m][r];
        }
        __syncthreads();
        if (wv == 0) {
#pragma unroll
            for (int r = 0; r < 4; ++r) {
                const float zf = accz[m][r] + rb[0][l][16 + r];
                const float zr = __builtin_amdgcn_rcpf(zf);
                const int row = i0 + m * 16 + hi * 4 + r;
#pragma unroll
                for (int n = 0; n < 4; ++n) {
                    const float o = (acc[m][n][r] + rb[0][l][n * 4 + r]) * zr;
                    out[row * HC + h * CC + n * 16 + lo] = o > 0.f ? o : 0.f;
                }
            }
        }
        if (m == 0) __syncthreads();   // protect buffer reuse for phase 1
    }
}

extern "C" void kernel_launch(void* const* d_in, const int* in_sizes, int n_in,
                              void* d_out, int out_size, void* d_ws, size_t ws_size,
                              hipStream_t stream)
{
    const float* x    = (const float*)d_in[0];
    const int*   adj  = (const int*)d_in[1];
    const float* W    = (const float*)d_in[2];
    const float* bias = (const float*)d_in[3];
    const float* attl = (const float*)d_in[4];
    const float* attr = (const float*)d_in[5];
    float* out = (float*)d_out;

    char* ws = (char*)d_ws;
    __bf16* xlS  = (__bf16*)(ws);                               // 4 MB (frag layout)
    float*  alT  = (float*)(ws + (4u << 20));                   // 128 KB
    float*  arT  = (float*)(ws + (4u << 20) + (128u << 10));    // 128 KB
    u64*    abit = (u64*)(ws + (4u << 20) + (256u << 10));      // 2 MB

    kA<<<dim3(PACK_BLOCKS + GEMM_BLOCKS), 256, 0, stream>>>(
        adj, abit, x, W, bias, attl, attr, xlS, alT, arT);
    k3_attn<<<dim3(NH, NN / 32), 512, 0, stream>>>(abit, xlS, alT, arT, out);
}

// Round 16
// 60.587 us; speedup vs baseline: 1.3653x; 1.3653x over previous
//
#include <hip/hip_runtime.h>
#include <hip/hip_bf16.h>

// GATConv on MI355X.
// Pipeline (2 kernels):
//   kA: blocks [0,512): x_l 64-row x 1-head tile GEMM (bf16 MFMA) -- GEMM FIRST
//       (R15 proved pack-first serializes the phases; GEMM 2/CU starts now and
//       pack fills remaining wave slots). Epilogue writes x_l in MFMA B-frag
//       order xlS[h][jw][s][n][lane][8] + per-head alpha_l/r (alpha_l x log2e).
//       blocks [512,4608): pack adj (64MB int32) -> 2MB bitmask, tile-transposed
//       [i>>5][jw][i&31]; 8 rows/wave-iter for MLP.
//   k3: block = (head, i-tile 32), 8 waves = 8 j-eighths.
//       Masking via 256x16B LDS LUT: mask-byte -> 4 u32 halfword masks, ANDed
//       with the cvt'd bf16 P (1 ds_read_b128 + 4 v_and per 8 elems replaces
//       8 bfe + 8 and; fma -> mul). -37% hot-loop VALU; LDS pipe is slack.
//       P = exp2(al2*ar) & mask in MFMA A-frag layout; acc += P @ x_l;
//       Z via MFMA ones-B. setprio(1) around exp+MFMA cluster.
//       2-phase x 3-round LDS tree reduce, out = relu(acc*rcp(Z)).
//   grid.x = 8 heads = 8 XCDs -> per-head xlS L2 locality.

#define NN    4096
#define NF    512
#define NH    8
#define CC    64
#define HC    512   // NH*CC
#define GEMM_BLOCKS 512
#define PACK_BLOCKS 4096

typedef __bf16 bf16x8 __attribute__((ext_vector_type(8)));
typedef __bf16 bf16x4 __attribute__((ext_vector_type(4)));
typedef float  f32x4  __attribute__((ext_vector_type(4)));
typedef int    i32x4  __attribute__((ext_vector_type(4)));
typedef unsigned int u32;
typedef unsigned long long u64;

__device__ __forceinline__ float exp2_raw(float x) {
    float r;
    asm("v_exp_f32 %0, %1" : "=v"(r) : "v"(x));
    return r;
}

// ---------------- kA: fused pack + projection GEMM + frag-layout store ----------------
__global__ __launch_bounds__(256) void kA(
    const int* __restrict__ adj, u64* __restrict__ bits,
    const float* __restrict__ X, const float* __restrict__ W,
    const float* __restrict__ bias, const float* __restrict__ attl,
    const float* __restrict__ attr, __bf16* __restrict__ xlS,
    float* __restrict__ alT, float* __restrict__ arT)
{
    const int tid = threadIdx.x;

    if (blockIdx.x >= GEMM_BLOCKS) {
        // ---- pack path: 8 rows per wave-iter (8 loads in flight), bitmask out ----
        const int bid  = blockIdx.x - GEMM_BLOCKS;
        const int lane = tid & 63;
        const int wid  = bid * 4 + (tid >> 6);      // 16384 waves
        for (int u = wid; u < 32768; u += 16384) {  // (4096/8 rowgroups) * 64 jw
            const int i0 = (u >> 6) * 8;
            const int jw = u & 63;
            const int ja = jw * 64 + lane;
            const u64 b0 = __ballot(adj[(i0 + 0) * NN + ja] != 0);
            const u64 b1 = __ballot(adj[(i0 + 1) * NN + ja] != 0);
            const u64 b2 = __ballot(adj[(i0 + 2) * NN + ja] != 0);
            const u64 b3 = __ballot(adj[(i0 + 3) * NN + ja] != 0);
            const u64 b4 = __ballot(adj[(i0 + 4) * NN + ja] != 0);
            const u64 b5 = __ballot(adj[(i0 + 5) * NN + ja] != 0);
            const u64 b6 = __ballot(adj[(i0 + 6) * NN + ja] != 0);
            const u64 b7 = __ballot(adj[(i0 + 7) * NN + ja] != 0);
            if (lane < 8) {
                const int r = lane;
                const u64 wr = (r < 4) ? ((r < 2) ? (r < 1 ? b0 : b1) : (r < 3 ? b2 : b3))
                                       : ((r < 6) ? (r < 5 ? b4 : b5) : (r < 7 ? b6 : b7));
                const int i = i0 + r;
                bits[((i >> 5) * 64 + jw) * 32 + (i & 31)] = wr;
            }
        }
        return;
    }

    // ---- GEMM path: one (64-node, 1-head) tile ----
    __shared__ __bf16 As[64][40];
    __shared__ __bf16 BsT[64][40];
    __shared__ __bf16 T[64][72];

    const int w  = tid >> 6;
    const int l  = tid & 63;
    const int lo = l & 15;
    const int hi = l >> 4;
    const int r0 = (blockIdx.x & 63) * 64;   // node base == jw*64
    const int h  = blockIdx.x >> 6;
    const int c0 = h * CC;
    const int wm = (w >> 1) * 32;
    const int wn = (w & 1) * 32;

    f32x4 acc[2][2];
#pragma unroll
    for (int m = 0; m < 2; ++m)
#pragma unroll
        for (int n = 0; n < 2; ++n) acc[m][n] = (f32x4){0.f, 0.f, 0.f, 0.f};

    const int arow = tid >> 3;
    const int acol = (tid & 7) * 4;
    const int brow = tid >> 4;
    const int bcol = (tid & 15) * 4;

    for (int k0 = 0; k0 < NF; k0 += 32) {
        __syncthreads();
#pragma unroll
        for (int p = 0; p < 2; ++p) {
            int r = arow + p * 32;
            float4 v = *reinterpret_cast<const float4*>(&X[(r0 + r) * NF + k0 + acol]);
            bf16x4 av;
            av[0] = (__bf16)v.x; av[1] = (__bf16)v.y; av[2] = (__bf16)v.z; av[3] = (__bf16)v.w;
            *reinterpret_cast<bf16x4*>(&As[r][acol]) = av;
        }
#pragma unroll
        for (int p = 0; p < 2; ++p) {
            int kk = brow + p * 16;
            float4 v = *reinterpret_cast<const float4*>(&W[(k0 + kk) * HC + c0 + bcol]);
            BsT[bcol + 0][kk] = (__bf16)v.x;
            BsT[bcol + 1][kk] = (__bf16)v.y;
            BsT[bcol + 2][kk] = (__bf16)v.z;
            BsT[bcol + 3][kk] = (__bf16)v.w;
        }
        __syncthreads();

        bf16x8 a[2], b[2];
#pragma unroll
        for (int m = 0; m < 2; ++m)
            a[m] = *reinterpret_cast<const bf16x8*>(&As[wm + m * 16 + lo][hi * 8]);
#pragma unroll
        for (int n = 0; n < 2; ++n)
            b[n] = *reinterpret_cast<const bf16x8*>(&BsT[wn + n * 16 + lo][hi * 8]);
#pragma unroll
        for (int m = 0; m < 2; ++m)
#pragma unroll
            for (int n = 0; n < 2; ++n)
                acc[m][n] = __builtin_amdgcn_mfma_f32_16x16x32_bf16(a[m], b[n], acc[m][n], 0, 0, 0);
    }

    // epilogue: bias + bf16 round into LDS tile T[node-in-tile][channel]
    __syncthreads();
#pragma unroll
    for (int n = 0; n < 2; ++n) {
        const float bv = bias[c0 + wn + n * 16 + lo];
#pragma unroll
        for (int m = 0; m < 2; ++m)
#pragma unroll
            for (int r = 0; r < 4; ++r)
                T[wm + m * 16 + hi * 4 + r][wn + n * 16 + lo] = (__bf16)(acc[m][n][r] + bv);
    }
    __syncthreads();

    // store in k3's B-fragment order: xlS[((h*64+jw)*2+s)*4+n][lane][8]
    {
        const int jw = blockIdx.x & 63;
#pragma unroll
        for (int p = 0; p < 2; ++p) {
            const int z   = tid + p * 256;
            const int s   = z >> 8;
            const int n   = (z >> 6) & 3;
            const int ln  = z & 63;
            const int hi2 = ln >> 4;
            const int lo2 = ln & 15;
            bf16x8 g;
#pragma unroll
            for (int e = 0; e < 8; ++e)
                g[e] = T[s * 32 + hi2 * 8 + e][n * 16 + lo2];
            *reinterpret_cast<bf16x8*>(
                &xlS[(size_t)((((h * 64 + jw) * 2 + s) * 4 + n) * 64 + ln) * 8]) = g;
        }
    }
    // alpha_l (scaled by log2e) / alpha_r for these 64 nodes
    {
        const int row = tid >> 2;
        const int q   = tid & 3;
        float pl = 0.f, pr = 0.f;
#pragma unroll
        for (int c = 0; c < 16; ++c) {
            const int cc = q * 16 + c;
            const float f = (float)T[row][cc];
            pl += f * attl[c0 + cc];
            pr += f * attr[c0 + cc];
        }
        pl += __shfl_xor(pl, 1); pl += __shfl_xor(pl, 2);
        pr += __shfl_xor(pr, 1); pr += __shfl_xor(pr, 2);
        if (q == 0) {
            alT[h * NN + r0 + row] = pl * 1.4426950408889634f;
            arT[h * NN + r0 + row] = pr;
        }
    }
}

// ---------------- k3: fused mask+exp+aggregate+Z+normalize+ReLU ----------------
__global__ __launch_bounds__(512) void k3_attn(
    const u64* __restrict__ bits, const __bf16* __restrict__ xlS,
    const float* __restrict__ alT, const float* __restrict__ arT,
    float* __restrict__ out)
{
    __shared__ float rb[4][64][21];   // [slot][lane][payload+pad] = 21.5 KB
    __shared__ u32 lut[256][4];       // mask-byte -> 4 halfword-mask words (4 KB)

    const int tid = threadIdx.x;
    const int wv  = tid >> 6;        // 8 waves : j-eighths
    const int l   = tid & 63;
    const int lo  = l & 15;
    const int hi  = l >> 4;
    const int h   = blockIdx.x;      // head (== XCD via round-robin dispatch)
    const int i0  = blockIdx.y * 32;
    const int off = hi * 8;          // bit offset within 32-bit mask word

    // build LUT (one entry per thread for tid<256)
    if (tid < 256) {
        const u32 b = (u32)tid;
        lut[tid][0] = ((b & 1u)   ? 0xFFFFu : 0u) | ((b & 2u)   ? 0xFFFF0000u : 0u);
        lut[tid][1] = ((b & 4u)   ? 0xFFFFu : 0u) | ((b & 8u)   ? 0xFFFF0000u : 0u);
        lut[tid][2] = ((b & 16u)  ? 0xFFFFu : 0u) | ((b & 32u)  ? 0xFFFF0000u : 0u);
        lut[tid][3] = ((b & 64u)  ? 0xFFFFu : 0u) | ((b & 128u) ? 0xFFFF0000u : 0u);
    }

    const float al20 = alT[h * NN + i0 + lo];
    const float al21 = alT[h * NN + i0 + 16 + lo];

    f32x4 acc[2][4];
    f32x4 accz[2];
#pragma unroll
    for (int m = 0; m < 2; ++m) {
        accz[m] = (f32x4){0.f, 0.f, 0.f, 0.f};
#pragma unroll
        for (int n = 0; n < 4; ++n) acc[m][n] = (f32x4){0.f, 0.f, 0.f, 0.f};
    }
    bf16x8 ones;
#pragma unroll
    for (int j = 0; j < 8; ++j) ones[j] = (__bf16)1.0f;

    const float* arp = &arT[h * NN];
    const __bf16* xs = xlS + (size_t)h * (64 * 4096);
    const u64* bT = bits + (size_t)blockIdx.y * 64 * 32;
    const int w0 = wv * 8;

    __syncthreads();   // LUT ready

#pragma unroll
    for (int it = 0; it < 8; ++it) {
        const int jw = w0 + it;
        const u64 ab0 = bT[jw * 32 + lo];
        const u64 ab1 = bT[jw * 32 + 16 + lo];
#pragma unroll
        for (int s = 0; s < 2; ++s) {
            const int jj = jw * 64 + s * 32 + hi * 8;
            const f32x4 rv0 = *reinterpret_cast<const f32x4*>(arp + jj);
            const f32x4 rv1 = *reinterpret_cast<const f32x4*>(arp + jj + 4);
            bf16x8 bX[4];
#pragma unroll
            for (int n = 0; n < 4; ++n)
                bX[n] = *reinterpret_cast<const bf16x8*>(
                    &xs[(jw * 2 + s) * 2048 + n * 512 + l * 8]);
            // boost this wave while it's in the exp+MFMA cluster
            __builtin_amdgcn_s_setprio(1);
#pragma unroll
            for (int m = 0; m < 2; ++m) {
                const u32 byte_ = ((u32)((m ? ab1 : ab0) >> (s * 32)) >> off) & 0xFFu;
                const i32x4 mk = *reinterpret_cast<const i32x4*>(&lut[byte_][0]);
                const float alm = m ? al21 : al20;
                const float p0 = exp2_raw(alm * rv0[0]);
                const float p1 = exp2_raw(alm * rv0[1]);
                const float p2 = exp2_raw(alm * rv0[2]);
                const float p3 = exp2_raw(alm * rv0[3]);
                const float p4 = exp2_raw(alm * rv1[0]);
                const float p5 = exp2_raw(alm * rv1[1]);
                const float p6 = exp2_raw(alm * rv1[2]);
                const float p7 = exp2_raw(alm * rv1[3]);
                bf16x8 aP;
                aP[0] = (__bf16)p0; aP[1] = (__bf16)p1; aP[2] = (__bf16)p2; aP[3] = (__bf16)p3;
                aP[4] = (__bf16)p4; aP[5] = (__bf16)p5; aP[6] = (__bf16)p6; aP[7] = (__bf16)p7;
                // bitwise AND: exact 0 on masked elements (bf16 positive finite)
                i32x4 ai = *reinterpret_cast<i32x4*>(&aP);
                ai &= mk;
                const bf16x8 aM = *reinterpret_cast<const bf16x8*>(&ai);
                accz[m] = __builtin_amdgcn_mfma_f32_16x16x32_bf16(aM, ones, accz[m], 0, 0, 0);
#pragma unroll
                for (int n = 0; n < 4; ++n)
                    acc[m][n] = __builtin_amdgcn_mfma_f32_16x16x32_bf16(aM, bX[n], acc[m][n], 0, 0, 0);
            }
            __builtin_amdgcn_s_setprio(0);
        }
    }

    // ---- 2-phase x 3-round LDS tree reduce across 8 waves ----
#pragma unroll
    for (int m = 0; m < 2; ++m) {
        if (wv >= 4) {
#pragma unroll
            for (int n = 0; n < 4; ++n)
#pragma unroll
                for (int r = 0; r < 4; ++r)
                    rb[wv - 4][l][n * 4 + r] = acc[m][n][r];
#pragma unroll
            for (int r = 0; r < 4; ++r)
                rb[wv - 4][l][16 + r] = accz[m][r];
        }
        __syncthreads();
        if (wv < 4) {
#pragma unroll
            for (int n = 0; n < 4; ++n)
#pragma unroll
                for (int r = 0; r < 4; ++r)
                    acc[m][n][r] += rb[wv][l][n * 4 + r];
#pragma unroll
            for (int r = 0; r < 4; ++r)
                accz[m][r] += rb[wv][l][16 + r];
        }
        __syncthreads();
        if (wv >= 2 && wv < 4) {
#pragma unroll
            for (int n = 0; n < 4; ++n)
#pragma unroll
                for (int r = 0; r < 4; ++r)
                    rb[wv - 2][l][n * 4 + r] = acc[m][n][r];
#pragma unroll
            for (int r = 0; r < 4; ++r)
                rb[wv - 2][l][16 + r] = accz[m][r];
        }
        __syncthreads();
        if (wv < 2) {
#pragma unroll
            for (int n = 0; n < 4; ++n)
#pragma unroll
                for (int r = 0; r < 4; ++r)
                    acc[m][n][r] += rb[wv][l][n * 4 + r];
#pragma unroll
            for (int r = 0; r < 4; ++r)
                accz[m][r] += rb[wv][l][16 + r];
        }
        __syncthreads();
        if (wv == 1) {
#pragma unroll
            for (int n = 0; n < 4; ++n)
#pragma unroll
                for (int r = 0; r < 4; ++r)
                    rb[0][l][n * 4 + r] = acc[m][n][r];
#pragma unroll
            for (int r = 0; r < 4; ++r)
                rb[0][l][16 + r] = accz[m][r];
        }
        __syncthreads();
        if (wv == 0) {
#pragma unroll
            for (int r = 0; r < 4; ++r) {
                const float zf = accz[m][r] + rb[0][l][16 + r];
                const float zr = __builtin_amdgcn_rcpf(zf);
                const int row = i0 + m * 16 + hi * 4 + r;
#pragma unroll
                for (int n = 0; n < 4; ++n) {
                    const float o = (acc[m][n][r] + rb[0][l][n * 4 + r]) * zr;
                    out[row * HC + h * CC + n * 16 + lo] = o > 0.f ? o : 0.f;
                }
            }
        }
        if (m == 0) __syncthreads();   // protect buffer reuse for phase 1
    }
}

extern "C" void kernel_launch(void* const* d_in, const int* in_sizes, int n_in,
                              void* d_out, int out_size, void* d_ws, size_t ws_size,
                              hipStream_t stream)
{
    const float* x    = (const float*)d_in[0];
    const int*   adj  = (const int*)d_in[1];
    const float* W    = (const float*)d_in[2];
    const float* bias = (const float*)d_in[3];
    const float* attl = (const float*)d_in[4];
    const float* attr = (const float*)d_in[5];
    float* out = (float*)d_out;

    char* ws = (char*)d_ws;
    __bf16* xlS  = (__bf16*)(ws);                               // 4 MB (frag layout)
    float*  alT  = (float*)(ws + (4u << 20));                   // 128 KB
    float*  arT  = (float*)(ws + (4u << 20) + (128u << 10));    // 128 KB
    u64*    abit = (u64*)(ws + (4u << 20) + (256u << 10));      // 2 MB

    kA<<<dim3(GEMM_BLOCKS + PACK_BLOCKS), 256, 0, stream>>>(
        adj, abit, x, W, bias, attl, attr, xlS, alT, arT);
    k3_attn<<<dim3(NH, NN / 32), 512, 0, stream>>>(abit, xlS, alT, arT, out);
}

// Round 17
// 60.358 us; speedup vs baseline: 1.3705x; 1.0038x over previous
//
#include <hip/hip_runtime.h>
#include <hip/hip_bf16.h>

// GATConv on MI355X.
// Pipeline (3 kernels):
//   kW: blocks [0,64): transpose+convert W (fp32 [k][c]) -> WTb (bf16 [c][k])
//       via LDS tiles. blocks [64,1088): convert X fp32 -> Xb bf16 (stream).
//       Moves all transpose/cvt work out of kA's hot loop (kA had 4.5M LDS
//       bank-conflict cycles from 2B scatter stores of the W transpose).
//   kA: blocks [0,512): x_l 64-row x 1-head tile GEMM; staging is now two 16B
//       bf16x8 copies per thread per K-step (no cvt, no scalar scatter).
//       Epilogue writes x_l in MFMA B-frag order xlS[h][jw][s][n][lane][8]
//       + per-head alpha_l/r (alpha_l x log2e).
//       blocks [512,4608): pack adj (64MB int32) -> 2MB bitmask, tile-transposed
//       [i>>5][jw][i&31]; 8 rows/wave-iter for MLP.
//   k3: R16 verbatim (proven plateau 40.3us): block = (head, i-tile 32), 8 waves
//       = 8 j-eighths; 256x16B LDS LUT masking (byte -> 4 halfword masks ANDed
//       post-cvt); P = exp2(al2*ar) & mask in MFMA A-frag layout; acc += P@x_l;
//       Z via MFMA ones-B; setprio(1) around exp+MFMA cluster;
//       2-phase x 3-round LDS tree reduce; out = relu(acc*rcp(Z)).
//   grid.x = 8 heads = 8 XCDs -> per-head xlS L2 locality.

#define NN    4096
#define NF    512
#define NH    8
#define CC    64
#define HC    512   // NH*CC
#define GEMM_BLOCKS 512
#define PACK_BLOCKS 4096

typedef __bf16 bf16x8 __attribute__((ext_vector_type(8)));
typedef __bf16 bf16x4 __attribute__((ext_vector_type(4)));
typedef float  f32x4  __attribute__((ext_vector_type(4)));
typedef int    i32x4  __attribute__((ext_vector_type(4)));
typedef unsigned int u32;
typedef unsigned long long u64;

__device__ __forceinline__ float exp2_raw(float x) {
    float r;
    asm("v_exp_f32 %0, %1" : "=v"(r) : "v"(x));
    return r;
}

// ---------------- kW: W transpose->bf16 + X convert->bf16 ----------------
__global__ __launch_bounds__(256) void kW(
    const float* __restrict__ W, const float* __restrict__ X,
    __bf16* __restrict__ WTb, __bf16* __restrict__ Xb)
{
    const int tid = threadIdx.x;

    if (blockIdx.x < 64) {
        // ---- W transpose tile: [k0..k0+64) x [c0..c0+64) ----
        __shared__ __bf16 Tt[64][72];
        const int c0 = (blockIdx.x & 7) * 64;
        const int k0 = (blockIdx.x >> 3) * 64;
#pragma unroll
        for (int p = 0; p < 4; ++p) {
            const int k  = (tid >> 4) + p * 16;
            const int c4 = (tid & 15) * 4;
            f32x4 v = *reinterpret_cast<const f32x4*>(&W[(k0 + k) * HC + c0 + c4]);
            Tt[c4 + 0][k] = (__bf16)v[0];
            Tt[c4 + 1][k] = (__bf16)v[1];
            Tt[c4 + 2][k] = (__bf16)v[2];
            Tt[c4 + 3][k] = (__bf16)v[3];
        }
        __syncthreads();
#pragma unroll
        for (int p = 0; p < 2; ++p) {
            const int c  = tid >> 2;
            const int kc = (tid & 3) + p * 4;
            bf16x8 g = *reinterpret_cast<const bf16x8*>(&Tt[c][kc * 8]);
            *reinterpret_cast<bf16x8*>(&WTb[(c0 + c) * NF + k0 + kc * 8]) = g;
        }
        return;
    }

    // ---- X convert: 8 f32 -> bf16x8 per thread, exactly one pass ----
    const int i = (blockIdx.x - 64) * 256 + tid;   // 0 .. 262143
    const float* xp = &X[i * 8];
    f32x4 v0 = *reinterpret_cast<const f32x4*>(xp);
    f32x4 v1 = *reinterpret_cast<const f32x4*>(xp + 4);
    bf16x8 g;
    g[0] = (__bf16)v0[0]; g[1] = (__bf16)v0[1]; g[2] = (__bf16)v0[2]; g[3] = (__bf16)v0[3];
    g[4] = (__bf16)v1[0]; g[5] = (__bf16)v1[1]; g[6] = (__bf16)v1[2]; g[7] = (__bf16)v1[3];
    *reinterpret_cast<bf16x8*>(&Xb[i * 8]) = g;
}

// ---------------- kA: fused pack + projection GEMM + frag-layout store ----------------
__global__ __launch_bounds__(256) void kA(
    const int* __restrict__ adj, u64* __restrict__ bits,
    const __bf16* __restrict__ Xb, const __bf16* __restrict__ WTb,
    const float* __restrict__ bias, const float* __restrict__ attl,
    const float* __restrict__ attr, __bf16* __restrict__ xlS,
    float* __restrict__ alT, float* __restrict__ arT)
{
    const int tid = threadIdx.x;

    if (blockIdx.x >= GEMM_BLOCKS) {
        // ---- pack path: 8 rows per wave-iter (8 loads in flight), bitmask out ----
        const int bid  = blockIdx.x - GEMM_BLOCKS;
        const int lane = tid & 63;
        const int wid  = bid * 4 + (tid >> 6);      // 16384 waves
        for (int u = wid; u < 32768; u += 16384) {  // (4096/8 rowgroups) * 64 jw
            const int i0 = (u >> 6) * 8;
            const int jw = u & 63;
            const int ja = jw * 64 + lane;
            const u64 b0 = __ballot(adj[(i0 + 0) * NN + ja] != 0);
            const u64 b1 = __ballot(adj[(i0 + 1) * NN + ja] != 0);
            const u64 b2 = __ballot(adj[(i0 + 2) * NN + ja] != 0);
            const u64 b3 = __ballot(adj[(i0 + 3) * NN + ja] != 0);
            const u64 b4 = __ballot(adj[(i0 + 4) * NN + ja] != 0);
            const u64 b5 = __ballot(adj[(i0 + 5) * NN + ja] != 0);
            const u64 b6 = __ballot(adj[(i0 + 6) * NN + ja] != 0);
            const u64 b7 = __ballot(adj[(i0 + 7) * NN + ja] != 0);
            if (lane < 8) {
                const int r = lane;
                const u64 wr = (r < 4) ? ((r < 2) ? (r < 1 ? b0 : b1) : (r < 3 ? b2 : b3))
                                       : ((r < 6) ? (r < 5 ? b4 : b5) : (r < 7 ? b6 : b7));
                const int i = i0 + r;
                bits[((i >> 5) * 64 + jw) * 32 + (i & 31)] = wr;
            }
        }
        return;
    }

    // ---- GEMM path: one (64-node, 1-head) tile; bf16 inputs, 16B staging ----
    __shared__ __bf16 As[64][40];
    __shared__ __bf16 BsT[64][40];
    __shared__ __bf16 T[64][72];

    const int w  = tid >> 6;
    const int l  = tid & 63;
    const int lo = l & 15;
    const int hi = l >> 4;
    const int r0 = (blockIdx.x & 63) * 64;   // node base == jw*64
    const int h  = blockIdx.x >> 6;
    const int c0 = h * CC;
    const int wm = (w >> 1) * 32;
    const int wn = (w & 1) * 32;

    f32x4 acc[2][2];
#pragma unroll
    for (int m = 0; m < 2; ++m)
#pragma unroll
        for (int n = 0; n < 2; ++n) acc[m][n] = (f32x4){0.f, 0.f, 0.f, 0.f};

    const int srow = tid >> 2;        // 0..63
    const int skc  = (tid & 3) * 8;   // 0,8,16,24

    for (int k0 = 0; k0 < NF; k0 += 32) {
        __syncthreads();
        {
            bf16x8 g = *reinterpret_cast<const bf16x8*>(&Xb[(r0 + srow) * NF + k0 + skc]);
            *reinterpret_cast<bf16x8*>(&As[srow][skc]) = g;
            bf16x8 t = *reinterpret_cast<const bf16x8*>(&WTb[(c0 + srow) * NF + k0 + skc]);
            *reinterpret_cast<bf16x8*>(&BsT[srow][skc]) = t;
        }
        __syncthreads();

        bf16x8 a[2], b[2];
#pragma unroll
        for (int m = 0; m < 2; ++m)
            a[m] = *reinterpret_cast<const bf16x8*>(&As[wm + m * 16 + lo][hi * 8]);
#pragma unroll
        for (int n = 0; n < 2; ++n)
            b[n] = *reinterpret_cast<const bf16x8*>(&BsT[wn + n * 16 + lo][hi * 8]);
#pragma unroll
        for (int m = 0; m < 2; ++m)
#pragma unroll
            for (int n = 0; n < 2; ++n)
                acc[m][n] = __builtin_amdgcn_mfma_f32_16x16x32_bf16(a[m], b[n], acc[m][n], 0, 0, 0);
    }

    // epilogue: bias + bf16 round into LDS tile T[node-in-tile][channel]
    __syncthreads();
#pragma unroll
    for (int n = 0; n < 2; ++n) {
        const float bv = bias[c0 + wn + n * 16 + lo];
#pragma unroll
        for (int m = 0; m < 2; ++m)
#pragma unroll
            for (int r = 0; r < 4; ++r)
                T[wm + m * 16 + hi * 4 + r][wn + n * 16 + lo] = (__bf16)(acc[m][n][r] + bv);
    }
    __syncthreads();

    // store in k3's B-fragment order: xlS[((h*64+jw)*2+s)*4+n][lane][8]
    {
        const int jw = blockIdx.x & 63;
#pragma unroll
        for (int p = 0; p < 2; ++p) {
            const int z   = tid + p * 256;
            const int s   = z >> 8;
            const int n   = (z >> 6) & 3;
            const int ln  = z & 63;
            const int hi2 = ln >> 4;
            const int lo2 = ln & 15;
            bf16x8 g;
#pragma unroll
            for (int e = 0; e < 8; ++e)
                g[e] = T[s * 32 + hi2 * 8 + e][n * 16 + lo2];
            *reinterpret_cast<bf16x8*>(
                &xlS[(size_t)((((h * 64 + jw) * 2 + s) * 4 + n) * 64 + ln) * 8]) = g;
        }
    }
    // alpha_l (scaled by log2e) / alpha_r for these 64 nodes
    {
        const int row = tid >> 2;
        const int q   = tid & 3;
        float pl = 0.f, pr = 0.f;
#pragma unroll
        for (int c = 0; c < 16; ++c) {
            const int cc = q * 16 + c;
            const float f = (float)T[row][cc];
            pl += f * attl[c0 + cc];
            pr += f * attr[c0 + cc];
        }
        pl += __shfl_xor(pl, 1); pl += __shfl_xor(pl, 2);
        pr += __shfl_xor(pr, 1); pr += __shfl_xor(pr, 2);
        if (q == 0) {
            alT[h * NN + r0 + row] = pl * 1.4426950408889634f;
            arT[h * NN + r0 + row] = pr;
        }
    }
}

// ---------------- k3: fused mask+exp+aggregate+Z+normalize+ReLU ----------------
__global__ __launch_bounds__(512) void k3_attn(
    const u64* __restrict__ bits, const __bf16* __restrict__ xlS,
    const float* __restrict__ alT, const float* __restrict__ arT,
    float* __restrict__ out)
{
    __shared__ float rb[4][64][21];   // [slot][lane][payload+pad] = 21.5 KB
    __shared__ u32 lut[256][4];       // mask-byte -> 4 halfword-mask words (4 KB)

    const int tid = threadIdx.x;
    const int wv  = tid >> 6;        // 8 waves : j-eighths
    const int l   = tid & 63;
    const int lo  = l & 15;
    const int hi  = l >> 4;
    const int h   = blockIdx.x;      // head (== XCD via round-robin dispatch)
    const int i0  = blockIdx.y * 32;
    const int off = hi * 8;          // bit offset within 32-bit mask word

    // build LUT (one entry per thread for tid<256)
    if (tid < 256) {
        const u32 b = (u32)tid;
        lut[tid][0] = ((b & 1u)   ? 0xFFFFu : 0u) | ((b & 2u)   ? 0xFFFF0000u : 0u);
        lut[tid][1] = ((b & 4u)   ? 0xFFFFu : 0u) | ((b & 8u)   ? 0xFFFF0000u : 0u);
        lut[tid][2] = ((b & 16u)  ? 0xFFFFu : 0u) | ((b & 32u)  ? 0xFFFF0000u : 0u);
        lut[tid][3] = ((b & 64u)  ? 0xFFFFu : 0u) | ((b & 128u) ? 0xFFFF0000u : 0u);
    }

    const float al20 = alT[h * NN + i0 + lo];
    const float al21 = alT[h * NN + i0 + 16 + lo];

    f32x4 acc[2][4];
    f32x4 accz[2];
#pragma unroll
    for (int m = 0; m < 2; ++m) {
        accz[m] = (f32x4){0.f, 0.f, 0.f, 0.f};
#pragma unroll
        for (int n = 0; n < 4; ++n) acc[m][n] = (f32x4){0.f, 0.f, 0.f, 0.f};
    }
    bf16x8 ones;
#pragma unroll
    for (int j = 0; j < 8; ++j) ones[j] = (__bf16)1.0f;

    const float* arp = &arT[h * NN];
    const __bf16* xs = xlS + (size_t)h * (64 * 4096);
    const u64* bT = bits + (size_t)blockIdx.y * 64 * 32;
    const int w0 = wv * 8;

    __syncthreads();   // LUT ready

#pragma unroll
    for (int it = 0; it < 8; ++it) {
        const int jw = w0 + it;
        const u64 ab0 = bT[jw * 32 + lo];
        const u64 ab1 = bT[jw * 32 + 16 + lo];
#pragma unroll
        for (int s = 0; s < 2; ++s) {
            const int jj = jw * 64 + s * 32 + hi * 8;
            const f32x4 rv0 = *reinterpret_cast<const f32x4*>(arp + jj);
            const f32x4 rv1 = *reinterpret_cast<const f32x4*>(arp + jj + 4);
            bf16x8 bX[4];
#pragma unroll
            for (int n = 0; n < 4; ++n)
                bX[n] = *reinterpret_cast<const bf16x8*>(
                    &xs[(jw * 2 + s) * 2048 + n * 512 + l * 8]);
            // boost this wave while it's in the exp+MFMA cluster
            __builtin_amdgcn_s_setprio(1);
#pragma unroll
            for (int m = 0; m < 2; ++m) {
                const u32 byte_ = ((u32)((m ? ab1 : ab0) >> (s * 32)) >> off) & 0xFFu;
                const i32x4 mk = *reinterpret_cast<const i32x4*>(&lut[byte_][0]);
                const float alm = m ? al21 : al20;
                const float p0 = exp2_raw(alm * rv0[0]);
                const float p1 = exp2_raw(alm * rv0[1]);
                const float p2 = exp2_raw(alm * rv0[2]);
                const float p3 = exp2_raw(alm * rv0[3]);
                const float p4 = exp2_raw(alm * rv1[0]);
                const float p5 = exp2_raw(alm * rv1[1]);
                const float p6 = exp2_raw(alm * rv1[2]);
                const float p7 = exp2_raw(alm * rv1[3]);
                bf16x8 aP;
                aP[0] = (__bf16)p0; aP[1] = (__bf16)p1; aP[2] = (__bf16)p2; aP[3] = (__bf16)p3;
                aP[4] = (__bf16)p4; aP[5] = (__bf16)p5; aP[6] = (__bf16)p6; aP[7] = (__bf16)p7;
                // bitwise AND: exact 0 on masked elements (bf16 positive finite)
                i32x4 ai = *reinterpret_cast<i32x4*>(&aP);
                ai &= mk;
                const bf16x8 aM = *reinterpret_cast<const bf16x8*>(&ai);
                accz[m] = __builtin_amdgcn_mfma_f32_16x16x32_bf16(aM, ones, accz[m], 0, 0, 0);
#pragma unroll
                for (int n = 0; n < 4; ++n)
                    acc[m][n] = __builtin_amdgcn_mfma_f32_16x16x32_bf16(aM, bX[n], acc[m][n], 0, 0, 0);
            }
            __builtin_amdgcn_s_setprio(0);
        }
    }

    // ---- 2-phase x 3-round LDS tree reduce across 8 waves ----
#pragma unroll
    for (int m = 0; m < 2; ++m) {
        if (wv >= 4) {
#pragma unroll
            for (int n = 0; n < 4; ++n)
#pragma unroll
                for (int r = 0; r < 4; ++r)
                    rb[wv - 4][l][n * 4 + r] = acc[m][n][r];
#pragma unroll
            for (int r = 0; r < 4; ++r)
                rb[wv - 4][l][16 + r] = accz[m][r];
        }
        __syncthreads();
        if (wv < 4) {
#pragma unroll
            for (int n = 0; n < 4; ++n)
#pragma unroll
                for (int r = 0; r < 4; ++r)
                    acc[m][n][r] += rb[wv][l][n * 4 + r];
#pragma unroll
            for (int r = 0; r < 4; ++r)
                accz[m][r] += rb[wv][l][16 + r];
        }
        __syncthreads();
        if (wv >= 2 && wv < 4) {
#pragma unroll
            for (int n = 0; n < 4; ++n)
#pragma unroll
                for (int r = 0; r < 4; ++r)
                    rb[wv - 2][l][n * 4 + r] = acc[m][n][r];
#pragma unroll
            for (int r = 0; r < 4; ++r)
                rb[wv - 2][l][16 + r] = accz[m][r];
        }
        __syncthreads();
        if (wv < 2) {
#pragma unroll
            for (int n = 0; n < 4; ++n)
#pragma unroll
                for (int r = 0; r < 4; ++r)
                    acc[m][n][r] += rb[wv][l][n * 4 + r];
#pragma unroll
            for (int r = 0; r < 4; ++r)
                accz[m][r] += rb[wv][l][16 + r];
        }
        __syncthreads();
        if (wv == 1) {
#pragma unroll
            for (int n = 0; n < 4; ++n)
#pragma unroll
                for (int r = 0; r < 4; ++r)
                    rb[0][l][n * 4 + r] = acc[m][n][r];
#pragma unroll
            for (int r = 0; r < 4; ++r)
                rb[0][l][16 + r] = accz[m][r];
        }
        __syncthreads();
        if (wv == 0) {
#pragma unroll
            for (int r = 0; r < 4; ++r) {
                const float zf = accz[m][r] + rb[0][l][16 + r];
                const float zr = __builtin_amdgcn_rcpf(zf);
                const int row = i0 + m * 16 + hi * 4 + r;
#pragma unroll
                for (int n = 0; n < 4; ++n) {
                    const float o = (acc[m][n][r] + rb[0][l][n * 4 + r]) * zr;
                    out[row * HC + h * CC + n * 16 + lo] = o > 0.f ? o : 0.f;
                }
            }
        }
        if (m == 0) __syncthreads();   // protect buffer reuse for phase 1
    }
}

extern "C" void kernel_launch(void* const* d_in, const int* in_sizes, int n_in,
                              void* d_out, int out_size, void* d_ws, size_t ws_size,
                              hipStream_t stream)
{
    const float* x    = (const float*)d_in[0];
    const int*   adj  = (const int*)d_in[1];
    const float* W    = (const float*)d_in[2];
    const float* bias = (const float*)d_in[3];
    const float* attl = (const float*)d_in[4];
    const float* attr = (const float*)d_in[5];
    float* out = (float*)d_out;

    char* ws = (char*)d_ws;
    __bf16* xlS  = (__bf16*)(ws);                               // 4 MB (frag layout)
    float*  alT  = (float*)(ws + (4u << 20));                   // 128 KB
    float*  arT  = (float*)(ws + (4u << 20) + (128u << 10));    // 128 KB
    u64*    abit = (u64*)(ws + (4u << 20) + (256u << 10));      // 2 MB
    __bf16* Xb   = (__bf16*)(ws + (6u << 20) + (256u << 10));   // 4 MB
    __bf16* WTb  = (__bf16*)(ws + (10u << 20) + (256u << 10));  // 512 KB

    kW<<<dim3(64 + 1024), 256, 0, stream>>>(W, x, WTb, Xb);
    kA<<<dim3(GEMM_BLOCKS + PACK_BLOCKS), 256, 0, stream>>>(
        adj, abit, Xb, WTb, bias, attl, attr, xlS, alT, arT);
    k3_attn<<<dim3(NH, NN / 32), 512, 0, stream>>>(abit, xlS, alT, arT, out);
}